// Round 10
// baseline (269.639 us; speedup 1.0000x reference)
//
#include <hip/hip_runtime.h>
#include <math.h>

// ---------------------------------------------------------------------------
// DGCNN-style network, B=8, N=2048, K=20, eval-mode BN.
// Round 10: restore r7's exact GEMM configuration (128-row tiles, register
// staging, padded-40 LDS; 64x64 tiles measured ~2.7x worse FLOP rate - m105).
// knn: pts staged as float4 with precomputed |p|^2 -> halves LDS issue count
// (1 ds_read_b128 vs b64+b32 pair) and kills the per-j |p|^2 recompute.
// head23 (l2+l3) fusion kept; l1 stays wide (1024 blocks - L1W is 4MB, an
// 8-block version would be per-CU L2-BW-bound).
// Trick (verified r1-r9): max_k lrelu(bn(h)) == lrelu(bn(max_k h)) for bn
// scale>=0, min_k when scale<0 -> gather reduces max AND min of pre-BN y.
// ---------------------------------------------------------------------------

#define WS_IDX      0            // int[16384*20]            1,310,720 B
#define WS_Y16      1310720     // half[16384*256]          8,388,608 B
#define WS_XCAT16   9699328     // half[16384*512]          16,777,216 B
#define WS_W16      26476544    // half[569344]             1,138,688 B
#define WS_FMAX     27615232    // uint[8*1024]             32,768 B
#define WS_FSUM     27648000    // float[8*1024]            32,768 B
#define WS_A1       27680768    // float[8*512]             16,384 B
// total ~27.7 MB

typedef _Float16 f16x8 __attribute__((ext_vector_type(8)));
typedef float f32x4 __attribute__((ext_vector_type(4)));

__device__ __forceinline__ float lrelu(float v) { return (v >= 0.f) ? v : 0.2f * v; }
__device__ __forceinline__ unsigned sortable_f32(float f) {
  unsigned b = __float_as_uint(f);
  return b ^ (((unsigned)((int)b >> 31)) | 0x80000000u);
}
__device__ __forceinline__ float desort_f32(unsigned u) {
  unsigned b = (u & 0x80000000u) ? (u ^ 0x80000000u) : ~u;
  return __uint_as_float(b);
}

// --------------------- KNN + edge1 + prep (one dispatch) --------------------
// Blocks [0,2048): knn for 8 query rows (4 waves x 2 queries/wave); coords +
// |p|^2 staged as float4 in LDS (32KB, single ds_read_b128 per candidate);
// pass1 lane-max -> 16-iter prefix bisection -> T; pass2 compacts candidates
// >= T via LDS atomics; 64-lane bitonic sort of ~(key<<32|2047-m) ==
// (key desc, m asc) exact tie-break; C>60 -> exact slow path. Then edge1
// in-place (lane=channel) -> xcat[:,0:64].
// Blocks [2048,2334): W2..W5 -> fp16 w16; zero fmax/fsum.
__global__ __launch_bounds__(256) void knn_prep_kernel(
    const float* __restrict__ x, const float* __restrict__ W1,
    const float* __restrict__ g1, const float* __restrict__ b1,
    const float* __restrict__ W2, const float* __restrict__ W3,
    const float* __restrict__ W4, const float* __restrict__ W5,
    _Float16* __restrict__ w16, unsigned* __restrict__ fzero,
    int* __restrict__ idxo, _Float16* __restrict__ xcat) {
  __shared__ float4 pts_s[2048];                // 32768 B
  __shared__ unsigned long long cand_s[8][60];  // 3840 B
  __shared__ unsigned cnt_s[8];
  __shared__ int sel_s[8][20];
  int tid = threadIdx.x;

  if (blockIdx.x >= 2048) {  // ---- prep branch ----
    int bid = blockIdx.x - 2048;
#pragma unroll
    for (int t = 0; t < 8; ++t) {
      int i = bid * 2048 + t * 256 + tid;
      if (i < 4096) w16[i] = (_Float16)W2[i];
      else if (i < 12288) w16[i] = (_Float16)W3[i - 4096];
      else if (i < 45056) w16[i] = (_Float16)W4[i - 12288];
      else if (i < 569344) w16[i] = (_Float16)W5[i - 45056];
      else fzero[i - 569344] = 0u;  // fmax (sortable 0 < any finite) + fsum
    }
    return;
  }

  int lwave = tid >> 6, lane = tid & 63;
  int qbase = blockIdx.x * 8;
  int b = qbase >> 11;
  int nbase = qbase & 2047;
  const float* xb = x + b * 6144;
#pragma unroll
  for (int i = 0; i < 8; ++i) {
    int m = tid + i * 256;
    float p0 = xb[m], p1 = xb[2048 + m], p2 = xb[4096 + m];
    pts_s[m] = make_float4(p0, p1, p2, p0 * p0 + p1 * p1 + p2 * p2);
  }
  if (lane == 0) cnt_s[lwave * 2] = 0, cnt_s[lwave * 2 + 1] = 0;
  __syncthreads();

  float4 q[2];
  unsigned lmax[2] = {0u, 0u};
#pragma unroll
  for (int qi = 0; qi < 2; ++qi) q[qi] = pts_s[nbase + lwave * 2 + qi];
  // pass 1: per-lane max key per query
  for (int j = 0; j < 32; ++j) {
    float4 p = pts_s[j * 64 + lane];
#pragma unroll
    for (int qi = 0; qi < 2; ++qi) {
      float nd = 2.0f * (q[qi].x * p.x + q[qi].y * p.y + q[qi].z * p.z) -
                 q[qi].w - p.w;
      unsigned key = sortable_f32(nd);
      lmax[qi] = (key > lmax[qi]) ? key : lmax[qi];
    }
  }
  // 16-iter bisection over the 16-bit prefix of the 64 lane-maxima
  unsigned lo[2] = {0u, 0u}, hi[2] = {0x8001u, 0x8001u};
  for (int it = 0; it < 16; ++it) {
#pragma unroll
    for (int qi = 0; qi < 2; ++qi) {
      unsigned mid = (lo[qi] + hi[qi] + 1) >> 1;
      int cnt = __popcll(__ballot(lmax[qi] >= (mid << 16)));
      if (cnt >= 20) lo[qi] = mid; else hi[qi] = mid;
    }
  }
  unsigned T[2] = {lo[0] << 16, lo[1] << 16};
  // pass 2: recompute keys, compact candidates >= T via LDS atomics
  for (int j = 0; j < 32; ++j) {
    int m = j * 64 + lane;
    float4 p = pts_s[m];
#pragma unroll
    for (int qi = 0; qi < 2; ++qi) {
      float nd = 2.0f * (q[qi].x * p.x + q[qi].y * p.y + q[qi].z * p.z) -
                 q[qi].w - p.w;
      unsigned key = sortable_f32(nd);
      if (key >= T[qi]) {
        unsigned pos = atomicAdd(&cnt_s[lwave * 2 + qi], 1u);
        if (pos < 60)
          cand_s[lwave * 2 + qi][pos] =
              (((unsigned long long)key) << 32) | (unsigned)(2047 - m);
      }
    }
  }
#pragma unroll
  for (int qi = 0; qi < 2; ++qi) {
    int qq = lwave * 2 + qi;
    int row = qbase + qq;
    int outb = row * 20;
    unsigned C = cnt_s[qq];  // wave-uniform
    if (C <= 60) {
      unsigned long long v = (lane < (int)C) ? ~cand_s[qq][lane] : ~0ull;
#pragma unroll
      for (int k = 2; k <= 64; k <<= 1) {
#pragma unroll
        for (int jj = k >> 1; jj > 0; jj >>= 1) {
          unsigned long long o = __shfl_xor(v, jj, 64);
          bool lower = (lane & jj) == 0;
          bool up = (lane & k) == 0;
          bool takeMin = (lower == up);
          bool sw = takeMin ? (o < v) : (o > v);
          v = sw ? o : v;
        }
      }
      if (lane < 20) {
        unsigned long long pack = ~v;
        int m = 2047 - (int)(pack & 0xFFFFFFFFu);
        idxo[outb + lane] = m;
        sel_s[qq][lane] = m;
      }
    } else {
      unsigned long long prev = ~0ull;
      for (int r = 0; r < 20; ++r) {
        unsigned long long best = 0ull;
        for (int j = 0; j < 32; ++j) {
          int m = j * 64 + lane;
          float4 p = pts_s[m];
          float nd = 2.0f * (q[qi].x * p.x + q[qi].y * p.y + q[qi].z * p.z) -
                     q[qi].w - p.w;
          unsigned long long pk =
              (((unsigned long long)sortable_f32(nd)) << 32) |
              (unsigned)(2047 - m);
          bool ok = (pk < prev) & (pk > best);
          best = ok ? pk : best;
        }
#pragma unroll
        for (int off = 1; off < 64; off <<= 1) {
          unsigned long long o = __shfl_xor(best, off, 64);
          best = (o > best) ? o : best;
        }
        int m = 2047 - (int)(best & 0xFFFFFFFFu);
        if (lane == 0) { idxo[outb + r] = m; sel_s[qq][r] = m; }
        prev = best;
      }
    }
  }
  // edge1 in-place: lane = channel, neighbors from staged LDS coords
  float w0 = W1[lane * 3 + 0], w1 = W1[lane * 3 + 1], w2 = W1[lane * 3 + 2];
  float inv = 1.0f / sqrtf(1.0f + 1e-5f);
  float sc = g1[lane] * inv, bi = b1[lane];
#pragma unroll
  for (int qi = 0; qi < 2; ++qi) {
    int qq = lwave * 2 + qi;
    int row = qbase + qq;
    float mx = -3.4e38f, mn = 3.4e38f;
#pragma unroll
    for (int k = 0; k < 20; ++k) {
      float4 p = pts_s[sel_s[qq][k]];
      float v = w0 * p.x + w1 * p.y + w2 * p.z;
      mx = fmaxf(mx, v);
      mn = fminf(mn, v);
    }
    float v = (sc >= 0.0f) ? mx : mn;
    xcat[row * 512 + lane] = (_Float16)lrelu(sc * v + bi);
  }
}

// --------------- gather max/min + BN + lrelu -> fp16 (f16x8) ----------------
template <int C, int COFF>
__global__ __launch_bounds__(256) void gmax_kernel(const _Float16* __restrict__ y,
                                                   const int* __restrict__ idx,
                                                   const float* __restrict__ g,
                                                   const float* __restrict__ bb,
                                                   _Float16* __restrict__ xcat) {
  constexpr int TP = C / 8;
  int e = blockIdx.x * 256 + threadIdx.x;
  int c8 = e & (TP - 1);
  int pg = e / TP;
  int b = pg >> 11;
  const int* ix = idx + pg * 20;
  int mm[20];
#pragma unroll
  for (int k = 0; k < 20; ++k) mm[k] = ix[k];
  int base = b * 2048 * C + c8 * 8;
  float mx[8], mn[8];
#pragma unroll
  for (int i = 0; i < 8; ++i) { mx[i] = -3.4e38f; mn[i] = 3.4e38f; }
#pragma unroll
  for (int k = 0; k < 20; ++k) {
    f16x8 v = *(const f16x8*)&y[base + mm[k] * C];
#pragma unroll
    for (int i = 0; i < 8; ++i) {
      float f = (float)v[i];
      mx[i] = fmaxf(mx[i], f);
      mn[i] = fminf(mn[i], f);
    }
  }
  float inv = 1.0f / sqrtf(1.0f + 1e-5f);
  f16x8 outv;
#pragma unroll
  for (int i = 0; i < 8; ++i) {
    float s = g[c8 * 8 + i] * inv;
    float v = (s >= 0.0f) ? mx[i] : mn[i];
    outv[i] = (_Float16)lrelu(s * v + bb[c8 * 8 + i]);
  }
  *(f16x8*)&xcat[pg * 512 + COFF + c8 * 8] = outv;
}

// ------------- fp16 MFMA GEMM (r7 exact): Y16 = Wh @ xcat-slice -------------
// BM=128, BN=min(COUT,128), BK=32. 4 waves: BN==128 -> 2x2 (64x64/wave),
// BN==64 -> 4x1 (32x64/wave). Register staging (compiler software-pipelines
// the global loads above the previous iteration's MFMA). Padded 40-half rows.
template <int CIN, int COUT, int XOFF>
__global__ __launch_bounds__(256) void gemm_mfma(const _Float16* __restrict__ Wh,
                                                 const _Float16* __restrict__ Xc,
                                                 _Float16* __restrict__ Y) {
  constexpr int BN = (COUT < 128) ? COUT : 128;
  constexpr int MT = (BN == 128) ? 4 : 2;
  __shared__ _Float16 Xs[128 * 40];
  __shared__ _Float16 Ws[BN * 40];
  int tid = threadIdx.x;
  int lane = tid & 63, w = tid >> 6;
  int wm = (BN == 128) ? (w & 1) : w;
  int wn = (BN == 128) ? (w >> 1) : 0;
  int col = lane & 15, quad = lane >> 4;
  int pg0 = blockIdx.x * 128;
  int o0 = blockIdx.y * BN;
  int r0 = tid >> 2;
  int c8 = (tid & 3) * 8;
  f32x4 acc[MT][4] = {};
  for (int k0 = 0; k0 < CIN; k0 += 32) {
    f16x8 xa = *(const f16x8*)&Xc[(pg0 + r0) * 512 + XOFF + k0 + c8];
    f16x8 xb2 = *(const f16x8*)&Xc[(pg0 + r0 + 64) * 512 + XOFF + k0 + c8];
    f16x8 wa = *(const f16x8*)&Wh[(o0 + r0) * CIN + k0 + c8];
    f16x8 wb;
    if (BN == 128) wb = *(const f16x8*)&Wh[(o0 + r0 + 64) * CIN + k0 + c8];
    __syncthreads();
    *(f16x8*)&Xs[r0 * 40 + c8] = xa;
    *(f16x8*)&Xs[(r0 + 64) * 40 + c8] = xb2;
    *(f16x8*)&Ws[r0 * 40 + c8] = wa;
    if (BN == 128) *(f16x8*)&Ws[(r0 + 64) * 40 + c8] = wb;
    __syncthreads();
    f16x8 af[MT], bf[4];
#pragma unroll
    for (int t = 0; t < MT; ++t)
      af[t] = *(const f16x8*)&Xs[(wm * (MT * 16) + t * 16 + col) * 40 + quad * 8];
#pragma unroll
    for (int t = 0; t < 4; ++t)
      bf[t] = *(const f16x8*)&Ws[(wn * 64 + t * 16 + col) * 40 + quad * 8];
#pragma unroll
    for (int mt = 0; mt < MT; ++mt)
#pragma unroll
      for (int nt = 0; nt < 4; ++nt)
        acc[mt][nt] = __builtin_amdgcn_mfma_f32_16x16x32_f16(af[mt], bf[nt],
                                                             acc[mt][nt], 0, 0, 0);
  }
#pragma unroll
  for (int mt = 0; mt < MT; ++mt)
#pragma unroll
    for (int nt = 0; nt < 4; ++nt)
#pragma unroll
      for (int r = 0; r < 4; ++r) {
        int p = pg0 + wm * (MT * 16) + mt * 16 + quad * 4 + r;
        int ch = o0 + wn * 64 + nt * 16 + col;
        Y[p * COUT + ch] = (_Float16)acc[mt][nt][r];
      }
}

// ------ gemm5: h = lrelu(bn(W5h @ xcat16)), fused pooled atomics (r7) -------
__global__ __launch_bounds__(256) void gemm5_kernel(
    const _Float16* __restrict__ Wh, const _Float16* __restrict__ Xc,
    const float* __restrict__ g5, const float* __restrict__ b5,
    unsigned* __restrict__ fmax, float* __restrict__ fsum) {
  __shared__ _Float16 Xs[128 * 40];
  __shared__ _Float16 Ws[128 * 40];
  __shared__ float pm[256], ps[256];
  int tid = threadIdx.x;
  int lane = tid & 63, w = tid >> 6;
  int wm = w & 1, wn = w >> 1;
  int col = lane & 15, quad = lane >> 4;
  int pg0 = blockIdx.x * 128;
  int o0 = blockIdx.y * 128;
  int r0 = tid >> 2;
  int c8 = (tid & 3) * 8;

  f32x4 acc[4][4] = {};
  for (int k0 = 0; k0 < 512; k0 += 32) {
    f16x8 xa = *(const f16x8*)&Xc[(pg0 + r0) * 512 + k0 + c8];
    f16x8 xb = *(const f16x8*)&Xc[(pg0 + r0 + 64) * 512 + k0 + c8];
    f16x8 wa = *(const f16x8*)&Wh[(o0 + r0) * 512 + k0 + c8];
    f16x8 wb = *(const f16x8*)&Wh[(o0 + r0 + 64) * 512 + k0 + c8];
    __syncthreads();
    *(f16x8*)&Xs[r0 * 40 + c8] = xa;
    *(f16x8*)&Xs[(r0 + 64) * 40 + c8] = xb;
    *(f16x8*)&Ws[r0 * 40 + c8] = wa;
    *(f16x8*)&Ws[(r0 + 64) * 40 + c8] = wb;
    __syncthreads();
    f16x8 af[4], bf[4];
#pragma unroll
    for (int t = 0; t < 4; ++t) {
      af[t] = *(const f16x8*)&Xs[(wm * 64 + t * 16 + col) * 40 + quad * 8];
      bf[t] = *(const f16x8*)&Ws[(wn * 64 + t * 16 + col) * 40 + quad * 8];
    }
#pragma unroll
    for (int mt = 0; mt < 4; ++mt)
#pragma unroll
      for (int nt = 0; nt < 4; ++nt)
        acc[mt][nt] = __builtin_amdgcn_mfma_f32_16x16x32_f16(af[mt], bf[nt],
                                                             acc[mt][nt], 0, 0, 0);
  }
  float inv = 1.0f / sqrtf(1.0f + 1e-5f);
#pragma unroll
  for (int nt = 0; nt < 4; ++nt) {
    int o = o0 + wn * 64 + nt * 16 + col;
    float sc = g5[o] * inv, bi = b5[o];
    float mx = -3.4e38f, sm = 0.f;
#pragma unroll
    for (int mt = 0; mt < 4; ++mt)
#pragma unroll
      for (int r = 0; r < 4; ++r) {
        float v = lrelu(acc[mt][nt][r] * sc + bi);
        mx = fmaxf(mx, v);
        sm += v;
      }
    mx = fmaxf(mx, __shfl_xor(mx, 16, 64));
    sm += __shfl_xor(sm, 16, 64);
    mx = fmaxf(mx, __shfl_xor(mx, 32, 64));
    sm += __shfl_xor(sm, 32, 64);
    if (quad == 0) {
      pm[wm * 128 + wn * 64 + nt * 16 + col] = mx;
      ps[wm * 128 + wn * 64 + nt * 16 + col] = sm;
    }
  }
  __syncthreads();
  if (tid < 128) {
    float m = fmaxf(pm[tid], pm[128 + tid]);
    float s = ps[tid] + ps[128 + tid];
    int b = pg0 >> 11;
    atomicMax(&fmax[b * 1024 + o0 + tid], sortable_f32(m));
    atomicAdd(&fsum[b * 1024 + o0 + tid], s);
  }
}

// ------------------------------ MLP head ------------------------------------
__global__ __launch_bounds__(256) void l1_kernel(const unsigned* __restrict__ fmax,
                                                 const float* __restrict__ fsum,
                                                 const float* __restrict__ L1W,
                                                 const float* __restrict__ g6,
                                                 const float* __restrict__ b6,
                                                 float* __restrict__ a1) {
  int gw = (blockIdx.x * 256 + threadIdx.x) >> 6;
  int lane = threadIdx.x & 63;
  int b = gw >> 9, o = gw & 511;
  float s = 0.f;
#pragma unroll
  for (int i = 0; i < 32; ++i) {
    int j = lane + i * 64;
    float fj = (j < 1024) ? desort_f32(fmax[b * 1024 + j])
                          : fsum[b * 1024 + j - 1024] * (1.0f / 2048.0f);
    s += fj * L1W[o * 2048 + j];
  }
#pragma unroll
  for (int off = 1; off < 64; off <<= 1) s += __shfl_xor(s, off, 64);
  if (lane == 0) {
    float scv = g6[o] / sqrtf(1.0f + 1e-5f);
    a1[b * 512 + o] = lrelu(s * scv + b6[o]);
  }
}

// ---- head23: l2 + l3 fused, one block per batch (a2 in LDS) ----------------
__global__ __launch_bounds__(256) void head23_kernel(
    const float* __restrict__ a1, const float* __restrict__ L2W,
    const float* __restrict__ L2b, const float* __restrict__ g7,
    const float* __restrict__ b7, const float* __restrict__ L3W,
    const float* __restrict__ L3b, float* __restrict__ out) {
  __shared__ float a2s[256];
  int b = blockIdx.x;
  int tid = threadIdx.x, lane = tid & 63, w = tid >> 6;
  const float* a1b = a1 + b * 512;
  float inv = 1.0f / sqrtf(1.0f + 1e-5f);
  for (int g8 = 0; g8 < 8; ++g8) {
    int obase = w * 64 + g8 * 8;
    float acc[8] = {};
#pragma unroll
    for (int i = 0; i < 8; ++i) {
      int j = lane + i * 64;
      float av = a1b[j];
#pragma unroll
      for (int oo = 0; oo < 8; ++oo) acc[oo] += av * L2W[(obase + oo) * 512 + j];
    }
#pragma unroll
    for (int oo = 0; oo < 8; ++oo) {
      float s = acc[oo];
#pragma unroll
      for (int off = 1; off < 64; off <<= 1) s += __shfl_xor(s, off, 64);
      if (lane == 0) {
        int o = obase + oo;
        float v = s + L2b[o];
        a2s[o] = lrelu(v * (g7[o] * inv) + b7[o]);
      }
    }
  }
  __syncthreads();
  for (int t = 0; t < 10; ++t) {
    int o = w + t * 4;
    float s = 0.f;
#pragma unroll
    for (int i = 0; i < 4; ++i) {
      int j = lane + i * 64;
      s += a2s[j] * L3W[o * 256 + j];
    }
#pragma unroll
    for (int off = 1; off < 64; off <<= 1) s += __shfl_xor(s, off, 64);
    if (lane == 0) out[b * 40 + o] = s + L3b[o];
  }
}

// ---------------------------------------------------------------------------
extern "C" void kernel_launch(void* const* d_in, const int* in_sizes, int n_in,
                              void* d_out, int out_size, void* d_ws, size_t ws_size,
                              hipStream_t stream) {
  const float* x = (const float*)d_in[0];
  const float* W1 = (const float*)d_in[1];
  const float* W2 = (const float*)d_in[2];
  const float* W3 = (const float*)d_in[3];
  const float* W4 = (const float*)d_in[4];
  const float* W5 = (const float*)d_in[5];
  const float* g1 = (const float*)d_in[6];  const float* b1 = (const float*)d_in[7];
  const float* g2 = (const float*)d_in[8];  const float* b2 = (const float*)d_in[9];
  const float* g3 = (const float*)d_in[10]; const float* b3 = (const float*)d_in[11];
  const float* g4 = (const float*)d_in[12]; const float* b4 = (const float*)d_in[13];
  const float* g5 = (const float*)d_in[14]; const float* b5 = (const float*)d_in[15];
  const float* g6 = (const float*)d_in[16]; const float* b6 = (const float*)d_in[17];
  const float* g7 = (const float*)d_in[18]; const float* b7 = (const float*)d_in[19];
  const float* L1W = (const float*)d_in[20];
  const float* L2W = (const float*)d_in[21];
  const float* L2b = (const float*)d_in[22];
  const float* L3W = (const float*)d_in[23];
  const float* L3b = (const float*)d_in[24];

  char* w = (char*)d_ws;
  int* idxb = (int*)(w + WS_IDX);
  _Float16* y16 = (_Float16*)(w + WS_Y16);
  _Float16* xcat16 = (_Float16*)(w + WS_XCAT16);
  _Float16* w16 = (_Float16*)(w + WS_W16);
  unsigned* fmax = (unsigned*)(w + WS_FMAX);
  float* fsum = (float*)(w + WS_FSUM);
  float* a1 = (float*)(w + WS_A1);

  knn_prep_kernel<<<2334, 256, 0, stream>>>(x, W1, g1, b1, W2, W3, W4, W5,
                                            w16, fmax, idxb, xcat16);
  gemm_mfma<64, 64, 0><<<dim3(128, 1), 256, 0, stream>>>(w16, xcat16, y16);
  gmax_kernel<64, 64><<<512, 256, 0, stream>>>(y16, idxb, g2, b2, xcat16);
  gemm_mfma<64, 128, 64><<<dim3(128, 1), 256, 0, stream>>>(w16 + 4096, xcat16, y16);
  gmax_kernel<128, 128><<<1024, 256, 0, stream>>>(y16, idxb, g3, b3, xcat16);
  gemm_mfma<128, 256, 128><<<dim3(128, 2), 256, 0, stream>>>(w16 + 12288, xcat16, y16);
  gmax_kernel<256, 256><<<2048, 256, 0, stream>>>(y16, idxb, g4, b4, xcat16);
  gemm5_kernel<<<dim3(128, 8), 256, 0, stream>>>(w16 + 45056, xcat16, g5, b5, fmax, fsum);
  l1_kernel<<<1024, 256, 0, stream>>>(fmax, fsum, L1W, g6, b6, a1);
  head23_kernel<<<8, 256, 0, stream>>>(a1, L2W, L2b, g7, b7, L3W, L3b,
                                       (float*)d_out);
}

// Round 11
// 234.561 us; speedup vs baseline: 1.1495x; 1.1495x over previous
//
#include <hip/hip_runtime.h>
#include <math.h>

// ---------------------------------------------------------------------------
// DGCNN-style network, B=8, N=2048, K=20, eval-mode BN.
// Round 11: byte-exact restoration of the r7 configuration (best measured:
// 237.3 us). Post-r7 deviations all regressed and are reverted:
//  - r8 async global_load_lds staging (+26us: barrier-bound DMA kills the
//    compiler's software pipelining; register staging kept).
//  - r9 64x64 small-GEMM tiles (+15us: 4 MFMA/barrier-pair amortization is
//    ~2.7x worse FLOP rate than 128-row tiles, m105).
//  - r8-r10 head23 fusion (+~10us: 8-block l2+l3 is latency-bound at 1.5%
//    machine occupancy; separate l2 (512 blk) + l3 (80 blk) restored).
//  - r10 float4 knn staging (+5-10us: ds_read_b128 ~12cyc == b64+b32 pair,
//    no issue win, and LDS 29->36.5KB cut occupancy 5->4 blocks/CU;
//    float3 staging restored).
// Trick (verified r1-r10): max_k lrelu(bn(h)) == lrelu(bn(max_k h)) for bn
// scale>=0, min_k when scale<0 -> gather reduces max AND min of pre-BN y.
// ---------------------------------------------------------------------------

#define WS_IDX      0            // int[16384*20]            1,310,720 B
#define WS_Y16      1310720     // half[16384*256]          8,388,608 B
#define WS_XCAT16   9699328     // half[16384*512]          16,777,216 B
#define WS_W16      26476544    // half[569344]             1,138,688 B
#define WS_FMAX     27615232    // uint[8*1024]             32,768 B
#define WS_FSUM     27648000    // float[8*1024]            32,768 B
#define WS_A1       27680768    // float[8*512]             16,384 B
#define WS_A2       27697152    // float[8*256]             8,192 B
// total ~27.7 MB

typedef _Float16 f16x8 __attribute__((ext_vector_type(8)));
typedef float f32x4 __attribute__((ext_vector_type(4)));

struct F3 { float x, y, z; };

__device__ __forceinline__ float lrelu(float v) { return (v >= 0.f) ? v : 0.2f * v; }
__device__ __forceinline__ unsigned sortable_f32(float f) {
  unsigned b = __float_as_uint(f);
  return b ^ (((unsigned)((int)b >> 31)) | 0x80000000u);
}
__device__ __forceinline__ float desort_f32(unsigned u) {
  unsigned b = (u & 0x80000000u) ? (u ^ 0x80000000u) : ~u;
  return __uint_as_float(b);
}

// --------------------- KNN + edge1 + prep (one dispatch) --------------------
// Blocks [0,2048): knn for 8 query rows (4 waves x 2 queries/wave); coords as
// float3 in LDS (24KB, |p|^2 recomputed, amortized over queries); pass1
// lane-max -> 16-iter prefix bisection -> T; pass2 compacts candidates >= T
// via LDS atomics; 64-lane bitonic sort of ~(key<<32|2047-m) ==
// (key desc, m asc) exact jax.lax.top_k tie-break; C>60 -> exact slow path.
// Then edge1 in-place (lane=channel) -> xcat[:,0:64].
// Blocks [2048,2334): W2..W5 -> fp16 w16; zero fmax/fsum.
__global__ __launch_bounds__(256) void knn_prep_kernel(
    const float* __restrict__ x, const float* __restrict__ W1,
    const float* __restrict__ g1, const float* __restrict__ b1,
    const float* __restrict__ W2, const float* __restrict__ W3,
    const float* __restrict__ W4, const float* __restrict__ W5,
    _Float16* __restrict__ w16, unsigned* __restrict__ fzero,
    int* __restrict__ idxo, _Float16* __restrict__ xcat) {
  __shared__ F3 pts_s[2048];                    // 24576 B
  __shared__ unsigned long long cand_s[8][60];  // 3840 B
  __shared__ unsigned cnt_s[8];
  __shared__ int sel_s[8][20];
  int tid = threadIdx.x;

  if (blockIdx.x >= 2048) {  // ---- prep branch ----
    int bid = blockIdx.x - 2048;
#pragma unroll
    for (int t = 0; t < 8; ++t) {
      int i = bid * 2048 + t * 256 + tid;
      if (i < 4096) w16[i] = (_Float16)W2[i];
      else if (i < 12288) w16[i] = (_Float16)W3[i - 4096];
      else if (i < 45056) w16[i] = (_Float16)W4[i - 12288];
      else if (i < 569344) w16[i] = (_Float16)W5[i - 45056];
      else fzero[i - 569344] = 0u;  // fmax (sortable 0 < any finite) + fsum
    }
    return;
  }

  int lwave = tid >> 6, lane = tid & 63;
  int qbase = blockIdx.x * 8;
  int b = qbase >> 11;
  int nbase = qbase & 2047;
  const float* xb = x + b * 6144;
#pragma unroll
  for (int i = 0; i < 8; ++i) {
    int m = tid + i * 256;
    F3 p; p.x = xb[m]; p.y = xb[2048 + m]; p.z = xb[4096 + m];
    pts_s[m] = p;
  }
  if (lane == 0) cnt_s[lwave * 2] = 0, cnt_s[lwave * 2 + 1] = 0;
  __syncthreads();

  F3 q[2];
  float qw[2];
  unsigned lmax[2] = {0u, 0u};
#pragma unroll
  for (int qi = 0; qi < 2; ++qi) {
    q[qi] = pts_s[nbase + lwave * 2 + qi];
    qw[qi] = q[qi].x * q[qi].x + q[qi].y * q[qi].y + q[qi].z * q[qi].z;
  }
  for (int j = 0; j < 32; ++j) {
    F3 p = pts_s[j * 64 + lane];
    float pw = p.x * p.x + p.y * p.y + p.z * p.z;
#pragma unroll
    for (int qi = 0; qi < 2; ++qi) {
      float nd = 2.0f * (q[qi].x * p.x + q[qi].y * p.y + q[qi].z * p.z) -
                 qw[qi] - pw;
      unsigned key = sortable_f32(nd);
      lmax[qi] = (key > lmax[qi]) ? key : lmax[qi];
    }
  }
  unsigned lo[2] = {0u, 0u}, hi[2] = {0x8001u, 0x8001u};
  for (int it = 0; it < 16; ++it) {
#pragma unroll
    for (int qi = 0; qi < 2; ++qi) {
      unsigned mid = (lo[qi] + hi[qi] + 1) >> 1;
      int cnt = __popcll(__ballot(lmax[qi] >= (mid << 16)));
      if (cnt >= 20) lo[qi] = mid; else hi[qi] = mid;
    }
  }
  unsigned T[2] = {lo[0] << 16, lo[1] << 16};
  for (int j = 0; j < 32; ++j) {
    int m = j * 64 + lane;
    F3 p = pts_s[m];
    float pw = p.x * p.x + p.y * p.y + p.z * p.z;
#pragma unroll
    for (int qi = 0; qi < 2; ++qi) {
      float nd = 2.0f * (q[qi].x * p.x + q[qi].y * p.y + q[qi].z * p.z) -
                 qw[qi] - pw;
      unsigned key = sortable_f32(nd);
      if (key >= T[qi]) {
        unsigned pos = atomicAdd(&cnt_s[lwave * 2 + qi], 1u);
        if (pos < 60)
          cand_s[lwave * 2 + qi][pos] =
              (((unsigned long long)key) << 32) | (unsigned)(2047 - m);
      }
    }
  }
#pragma unroll
  for (int qi = 0; qi < 2; ++qi) {
    int qq = lwave * 2 + qi;
    int row = qbase + qq;
    int outb = row * 20;
    unsigned C = cnt_s[qq];  // wave-uniform
    if (C <= 60) {
      unsigned long long v = (lane < (int)C) ? ~cand_s[qq][lane] : ~0ull;
#pragma unroll
      for (int k = 2; k <= 64; k <<= 1) {
#pragma unroll
        for (int jj = k >> 1; jj > 0; jj >>= 1) {
          unsigned long long o = __shfl_xor(v, jj, 64);
          bool lower = (lane & jj) == 0;
          bool up = (lane & k) == 0;
          bool takeMin = (lower == up);
          bool sw = takeMin ? (o < v) : (o > v);
          v = sw ? o : v;
        }
      }
      if (lane < 20) {
        unsigned long long pack = ~v;
        int m = 2047 - (int)(pack & 0xFFFFFFFFu);
        idxo[outb + lane] = m;
        sel_s[qq][lane] = m;
      }
    } else {
      unsigned long long prev = ~0ull;
      for (int r = 0; r < 20; ++r) {
        unsigned long long best = 0ull;
        for (int j = 0; j < 32; ++j) {
          int m = j * 64 + lane;
          F3 p = pts_s[m];
          float pw = p.x * p.x + p.y * p.y + p.z * p.z;
          float nd = 2.0f * (q[qi].x * p.x + q[qi].y * p.y + q[qi].z * p.z) -
                     qw[qi] - pw;
          unsigned long long pk =
              (((unsigned long long)sortable_f32(nd)) << 32) |
              (unsigned)(2047 - m);
          bool ok = (pk < prev) & (pk > best);
          best = ok ? pk : best;
        }
#pragma unroll
        for (int off = 1; off < 64; off <<= 1) {
          unsigned long long o = __shfl_xor(best, off, 64);
          best = (o > best) ? o : best;
        }
        int m = 2047 - (int)(best & 0xFFFFFFFFu);
        if (lane == 0) { idxo[outb + r] = m; sel_s[qq][r] = m; }
        prev = best;
      }
    }
  }
  float w0 = W1[lane * 3 + 0], w1 = W1[lane * 3 + 1], w2 = W1[lane * 3 + 2];
  float inv = 1.0f / sqrtf(1.0f + 1e-5f);
  float sc = g1[lane] * inv, bi = b1[lane];
#pragma unroll
  for (int qi = 0; qi < 2; ++qi) {
    int qq = lwave * 2 + qi;
    int row = qbase + qq;
    float mx = -3.4e38f, mn = 3.4e38f;
#pragma unroll
    for (int k = 0; k < 20; ++k) {
      F3 p = pts_s[sel_s[qq][k]];
      float v = w0 * p.x + w1 * p.y + w2 * p.z;
      mx = fmaxf(mx, v);
      mn = fminf(mn, v);
    }
    float v = (sc >= 0.0f) ? mx : mn;
    xcat[row * 512 + lane] = (_Float16)lrelu(sc * v + bi);
  }
}

// --------------- gather max/min + BN + lrelu -> fp16 (f16x8) ----------------
template <int C, int COFF>
__global__ __launch_bounds__(256) void gmax_kernel(const _Float16* __restrict__ y,
                                                   const int* __restrict__ idx,
                                                   const float* __restrict__ g,
                                                   const float* __restrict__ bb,
                                                   _Float16* __restrict__ xcat) {
  constexpr int TP = C / 8;
  int e = blockIdx.x * 256 + threadIdx.x;
  int c8 = e & (TP - 1);
  int pg = e / TP;
  int b = pg >> 11;
  const int* ix = idx + pg * 20;
  int mm[20];
#pragma unroll
  for (int k = 0; k < 20; ++k) mm[k] = ix[k];
  int base = b * 2048 * C + c8 * 8;
  float mx[8], mn[8];
#pragma unroll
  for (int i = 0; i < 8; ++i) { mx[i] = -3.4e38f; mn[i] = 3.4e38f; }
#pragma unroll
  for (int k = 0; k < 20; ++k) {
    f16x8 v = *(const f16x8*)&y[base + mm[k] * C];
#pragma unroll
    for (int i = 0; i < 8; ++i) {
      float f = (float)v[i];
      mx[i] = fmaxf(mx[i], f);
      mn[i] = fminf(mn[i], f);
    }
  }
  float inv = 1.0f / sqrtf(1.0f + 1e-5f);
  f16x8 outv;
#pragma unroll
  for (int i = 0; i < 8; ++i) {
    float s = g[c8 * 8 + i] * inv;
    float v = (s >= 0.0f) ? mx[i] : mn[i];
    outv[i] = (_Float16)lrelu(s * v + bb[c8 * 8 + i]);
  }
  *(f16x8*)&xcat[pg * 512 + COFF + c8 * 8] = outv;
}

// ------------- fp16 MFMA GEMM (r7 exact): Y16 = Wh @ xcat-slice -------------
// BM=128, BN=min(COUT,128), BK=32. 4 waves: BN==128 -> 2x2 (64x64/wave),
// BN==64 -> 4x1 (32x64/wave). Register staging (compiler software-pipelines
// the global loads above the previous iteration's MFMA). Padded 40-half rows.
template <int CIN, int COUT, int XOFF>
__global__ __launch_bounds__(256) void gemm_mfma(const _Float16* __restrict__ Wh,
                                                 const _Float16* __restrict__ Xc,
                                                 _Float16* __restrict__ Y) {
  constexpr int BN = (COUT < 128) ? COUT : 128;
  constexpr int MT = (BN == 128) ? 4 : 2;
  __shared__ _Float16 Xs[128 * 40];
  __shared__ _Float16 Ws[BN * 40];
  int tid = threadIdx.x;
  int lane = tid & 63, w = tid >> 6;
  int wm = (BN == 128) ? (w & 1) : w;
  int wn = (BN == 128) ? (w >> 1) : 0;
  int col = lane & 15, quad = lane >> 4;
  int pg0 = blockIdx.x * 128;
  int o0 = blockIdx.y * BN;
  int r0 = tid >> 2;
  int c8 = (tid & 3) * 8;
  f32x4 acc[MT][4] = {};
  for (int k0 = 0; k0 < CIN; k0 += 32) {
    f16x8 xa = *(const f16x8*)&Xc[(pg0 + r0) * 512 + XOFF + k0 + c8];
    f16x8 xb2 = *(const f16x8*)&Xc[(pg0 + r0 + 64) * 512 + XOFF + k0 + c8];
    f16x8 wa = *(const f16x8*)&Wh[(o0 + r0) * CIN + k0 + c8];
    f16x8 wb;
    if (BN == 128) wb = *(const f16x8*)&Wh[(o0 + r0 + 64) * CIN + k0 + c8];
    __syncthreads();
    *(f16x8*)&Xs[r0 * 40 + c8] = xa;
    *(f16x8*)&Xs[(r0 + 64) * 40 + c8] = xb2;
    *(f16x8*)&Ws[r0 * 40 + c8] = wa;
    if (BN == 128) *(f16x8*)&Ws[(r0 + 64) * 40 + c8] = wb;
    __syncthreads();
    f16x8 af[MT], bf[4];
#pragma unroll
    for (int t = 0; t < MT; ++t)
      af[t] = *(const f16x8*)&Xs[(wm * (MT * 16) + t * 16 + col) * 40 + quad * 8];
#pragma unroll
    for (int t = 0; t < 4; ++t)
      bf[t] = *(const f16x8*)&Ws[(wn * 64 + t * 16 + col) * 40 + quad * 8];
#pragma unroll
    for (int mt = 0; mt < MT; ++mt)
#pragma unroll
      for (int nt = 0; nt < 4; ++nt)
        acc[mt][nt] = __builtin_amdgcn_mfma_f32_16x16x32_f16(af[mt], bf[nt],
                                                             acc[mt][nt], 0, 0, 0);
  }
#pragma unroll
  for (int mt = 0; mt < MT; ++mt)
#pragma unroll
    for (int nt = 0; nt < 4; ++nt)
#pragma unroll
      for (int r = 0; r < 4; ++r) {
        int p = pg0 + wm * (MT * 16) + mt * 16 + quad * 4 + r;
        int ch = o0 + wn * 64 + nt * 16 + col;
        Y[p * COUT + ch] = (_Float16)acc[mt][nt][r];
      }
}

// ------ gemm5: h = lrelu(bn(W5h @ xcat16)), fused pooled atomics (r7) -------
__global__ __launch_bounds__(256) void gemm5_kernel(
    const _Float16* __restrict__ Wh, const _Float16* __restrict__ Xc,
    const float* __restrict__ g5, const float* __restrict__ b5,
    unsigned* __restrict__ fmax, float* __restrict__ fsum) {
  __shared__ _Float16 Xs[128 * 40];
  __shared__ _Float16 Ws[128 * 40];
  __shared__ float pm[256], ps[256];
  int tid = threadIdx.x;
  int lane = tid & 63, w = tid >> 6;
  int wm = w & 1, wn = w >> 1;
  int col = lane & 15, quad = lane >> 4;
  int pg0 = blockIdx.x * 128;
  int o0 = blockIdx.y * 128;
  int r0 = tid >> 2;
  int c8 = (tid & 3) * 8;

  f32x4 acc[4][4] = {};
  for (int k0 = 0; k0 < 512; k0 += 32) {
    f16x8 xa = *(const f16x8*)&Xc[(pg0 + r0) * 512 + k0 + c8];
    f16x8 xb = *(const f16x8*)&Xc[(pg0 + r0 + 64) * 512 + k0 + c8];
    f16x8 wa = *(const f16x8*)&Wh[(o0 + r0) * 512 + k0 + c8];
    f16x8 wb = *(const f16x8*)&Wh[(o0 + r0 + 64) * 512 + k0 + c8];
    __syncthreads();
    *(f16x8*)&Xs[r0 * 40 + c8] = xa;
    *(f16x8*)&Xs[(r0 + 64) * 40 + c8] = xb;
    *(f16x8*)&Ws[r0 * 40 + c8] = wa;
    *(f16x8*)&Ws[(r0 + 64) * 40 + c8] = wb;
    __syncthreads();
    f16x8 af[4], bf[4];
#pragma unroll
    for (int t = 0; t < 4; ++t) {
      af[t] = *(const f16x8*)&Xs[(wm * 64 + t * 16 + col) * 40 + quad * 8];
      bf[t] = *(const f16x8*)&Ws[(wn * 64 + t * 16 + col) * 40 + quad * 8];
    }
#pragma unroll
    for (int mt = 0; mt < 4; ++mt)
#pragma unroll
      for (int nt = 0; nt < 4; ++nt)
        acc[mt][nt] = __builtin_amdgcn_mfma_f32_16x16x32_f16(af[mt], bf[nt],
                                                             acc[mt][nt], 0, 0, 0);
  }
  float inv = 1.0f / sqrtf(1.0f + 1e-5f);
#pragma unroll
  for (int nt = 0; nt < 4; ++nt) {
    int o = o0 + wn * 64 + nt * 16 + col;
    float sc = g5[o] * inv, bi = b5[o];
    float mx = -3.4e38f, sm = 0.f;
#pragma unroll
    for (int mt = 0; mt < 4; ++mt)
#pragma unroll
      for (int r = 0; r < 4; ++r) {
        float v = lrelu(acc[mt][nt][r] * sc + bi);
        mx = fmaxf(mx, v);
        sm += v;
      }
    mx = fmaxf(mx, __shfl_xor(mx, 16, 64));
    sm += __shfl_xor(sm, 16, 64);
    mx = fmaxf(mx, __shfl_xor(mx, 32, 64));
    sm += __shfl_xor(sm, 32, 64);
    if (quad == 0) {
      pm[wm * 128 + wn * 64 + nt * 16 + col] = mx;
      ps[wm * 128 + wn * 64 + nt * 16 + col] = sm;
    }
  }
  __syncthreads();
  if (tid < 128) {
    float m = fmaxf(pm[tid], pm[128 + tid]);
    float s = ps[tid] + ps[128 + tid];
    int b = pg0 >> 11;
    atomicMax(&fmax[b * 1024 + o0 + tid], sortable_f32(m));
    atomicAdd(&fsum[b * 1024 + o0 + tid], s);
  }
}

// ------------------------------ MLP head ------------------------------------
__global__ __launch_bounds__(256) void l1_kernel(const unsigned* __restrict__ fmax,
                                                 const float* __restrict__ fsum,
                                                 const float* __restrict__ L1W,
                                                 const float* __restrict__ g6,
                                                 const float* __restrict__ b6,
                                                 float* __restrict__ a1) {
  int gw = (blockIdx.x * 256 + threadIdx.x) >> 6;
  int lane = threadIdx.x & 63;
  int b = gw >> 9, o = gw & 511;
  float s = 0.f;
#pragma unroll
  for (int i = 0; i < 32; ++i) {
    int j = lane + i * 64;
    float fj = (j < 1024) ? desort_f32(fmax[b * 1024 + j])
                          : fsum[b * 1024 + j - 1024] * (1.0f / 2048.0f);
    s += fj * L1W[o * 2048 + j];
  }
#pragma unroll
  for (int off = 1; off < 64; off <<= 1) s += __shfl_xor(s, off, 64);
  if (lane == 0) {
    float scv = g6[o] / sqrtf(1.0f + 1e-5f);
    a1[b * 512 + o] = lrelu(s * scv + b6[o]);
  }
}

__global__ __launch_bounds__(256) void l2_kernel(const float* __restrict__ a1,
                                                 const float* __restrict__ L2W,
                                                 const float* __restrict__ L2b,
                                                 const float* __restrict__ g7,
                                                 const float* __restrict__ b7,
                                                 float* __restrict__ a2) {
  int gw = (blockIdx.x * 256 + threadIdx.x) >> 6;  // 2048 waves
  int lane = threadIdx.x & 63;
  int b = gw >> 8, o = gw & 255;
  float s = 0.f;
#pragma unroll
  for (int i = 0; i < 8; ++i) {
    int j = lane + i * 64;
    s += a1[b * 512 + j] * L2W[o * 512 + j];
  }
#pragma unroll
  for (int off = 1; off < 64; off <<= 1) s += __shfl_xor(s, off, 64);
  if (lane == 0) {
    float v = s + L2b[o];
    float scv = g7[o] / sqrtf(1.0f + 1e-5f);
    a2[b * 256 + o] = lrelu(v * scv + b7[o]);
  }
}

__global__ __launch_bounds__(256) void l3_kernel(const float* __restrict__ a2,
                                                 const float* __restrict__ L3W,
                                                 const float* __restrict__ L3b,
                                                 float* __restrict__ out) {
  int gw = (blockIdx.x * 256 + threadIdx.x) >> 6;  // 320 waves
  int lane = threadIdx.x & 63;
  int b = gw / 40, o = gw % 40;
  float s = 0.f;
#pragma unroll
  for (int i = 0; i < 4; ++i) {
    int j = lane + i * 64;
    s += a2[b * 256 + j] * L3W[o * 256 + j];
  }
#pragma unroll
  for (int off = 1; off < 64; off <<= 1) s += __shfl_xor(s, off, 64);
  if (lane == 0) out[b * 40 + o] = s + L3b[o];
}

// ---------------------------------------------------------------------------
extern "C" void kernel_launch(void* const* d_in, const int* in_sizes, int n_in,
                              void* d_out, int out_size, void* d_ws, size_t ws_size,
                              hipStream_t stream) {
  const float* x = (const float*)d_in[0];
  const float* W1 = (const float*)d_in[1];
  const float* W2 = (const float*)d_in[2];
  const float* W3 = (const float*)d_in[3];
  const float* W4 = (const float*)d_in[4];
  const float* W5 = (const float*)d_in[5];
  const float* g1 = (const float*)d_in[6];  const float* b1 = (const float*)d_in[7];
  const float* g2 = (const float*)d_in[8];  const float* b2 = (const float*)d_in[9];
  const float* g3 = (const float*)d_in[10]; const float* b3 = (const float*)d_in[11];
  const float* g4 = (const float*)d_in[12]; const float* b4 = (const float*)d_in[13];
  const float* g5 = (const float*)d_in[14]; const float* b5 = (const float*)d_in[15];
  const float* g6 = (const float*)d_in[16]; const float* b6 = (const float*)d_in[17];
  const float* g7 = (const float*)d_in[18]; const float* b7 = (const float*)d_in[19];
  const float* L1W = (const float*)d_in[20];
  const float* L2W = (const float*)d_in[21];
  const float* L2b = (const float*)d_in[22];
  const float* L3W = (const float*)d_in[23];
  const float* L3b = (const float*)d_in[24];

  char* w = (char*)d_ws;
  int* idxb = (int*)(w + WS_IDX);
  _Float16* y16 = (_Float16*)(w + WS_Y16);
  _Float16* xcat16 = (_Float16*)(w + WS_XCAT16);
  _Float16* w16 = (_Float16*)(w + WS_W16);
  unsigned* fmax = (unsigned*)(w + WS_FMAX);
  float* fsum = (float*)(w + WS_FSUM);
  float* a1 = (float*)(w + WS_A1);
  float* a2 = (float*)(w + WS_A2);

  knn_prep_kernel<<<2334, 256, 0, stream>>>(x, W1, g1, b1, W2, W3, W4, W5,
                                            w16, fmax, idxb, xcat16);
  gemm_mfma<64, 64, 0><<<dim3(128, 1), 256, 0, stream>>>(w16, xcat16, y16);
  gmax_kernel<64, 64><<<512, 256, 0, stream>>>(y16, idxb, g2, b2, xcat16);
  gemm_mfma<64, 128, 64><<<dim3(128, 1), 256, 0, stream>>>(w16 + 4096, xcat16, y16);
  gmax_kernel<128, 128><<<1024, 256, 0, stream>>>(y16, idxb, g3, b3, xcat16);
  gemm_mfma<128, 256, 128><<<dim3(128, 2), 256, 0, stream>>>(w16 + 12288, xcat16, y16);
  gmax_kernel<256, 256><<<2048, 256, 0, stream>>>(y16, idxb, g4, b4, xcat16);
  gemm5_kernel<<<dim3(128, 8), 256, 0, stream>>>(w16 + 45056, xcat16, g5, b5, fmax, fsum);
  l1_kernel<<<1024, 256, 0, stream>>>(fmax, fsum, L1W, g6, b6, a1);
  l2_kernel<<<512, 256, 0, stream>>>(a1, L2W, L2b, g7, b7, a2);
  l3_kernel<<<80, 256, 0, stream>>>(a2, L3W, L3b, (float*)d_out);
}